// Round 7
// baseline (17.139 us; speedup 1.0000x reference)
//
#include <hip/hip_runtime.h>

// Problem constants (match reference)
#define BATCH     16
#define SEQ_N     1024
#define EMBED_DIM 256
#define NTILE     16     // n-values per block
#define DHALF     128    // d-values per block (half a row)
#define S4        33     // LDS stride in f32x4 (=132 floats): transpose read 2-way (free)

typedef float f32x4 __attribute__((ext_vector_type(4)));

// out[b][d][n] = embedding[seq[b][n]][d]
//
// Block = (b, n-tile of 16, d-half of 128), 256 threads. Grid 2048 ->
// 8 blocks/CU x 4 waves = 32 waves/CU: max occupancy with 2x the independent
// barrier domains of the 512-thread variant (phases of different blocks
// overlap; barriers sync only 4 waves).
// Loads: 512B contiguous row-halves. Stores: 64B full-line NT chunks per d
// (NT avoids RFO/write-allocate; proven +1.8us in R4-vs-R5 A/B).
__global__ __launch_bounds__(256) void
embed_gather_transpose(const int* __restrict__ seq,
                       const float* __restrict__ emb,
                       float* __restrict__ out) {
    __shared__ f32x4 lds4[NTILE * S4];   // 8.4 KB
    const float* lds = reinterpret_cast<const float*>(lds4);

    const int dhalf = blockIdx.x & 1;           // 2 d-halves
    const int nt    = (blockIdx.x >> 1) & 63;   // 64 n-tiles
    const int b     = blockIdx.x >> 7;          // 16 batches
    const int n0    = nt << 4;
    const int d0    = dhalf << 7;

    const int* seqb = seq + b * SEQ_N + n0;

    // ---- load phase: 16 rows x 32 f32x4 (512B row-half) = 512, 2/thread ----
    // per wave-instr: two contiguous 512B segments -> coalesced.
#pragma unroll
    for (int i = 0; i < 2; ++i) {
        const int flat = i * 256 + threadIdx.x;  // 0..511
        const int nn   = flat >> 5;              // row in tile (32 f4 per half)
        const int c4   = flat & 31;              // f32x4 column within half
        const int row  = seqb[nn];               // 64B line, L1 broadcast
        lds4[nn * S4 + c4] =
            reinterpret_cast<const f32x4*>(emb + (size_t)row * EMBED_DIM + d0)[c4];
    }
    __syncthreads();

    // ---- store phase: 128 d x 4 f32x4 (16 n) = 512, 2/thread ----
    // 4 lanes emit one contiguous 64B line-aligned chunk per d.
    // Transpose read banks: (16q + d) mod 32 -> 2-way = free.
    float* outb = out + ((size_t)b * EMBED_DIM + d0) * SEQ_N + n0;
#pragma unroll
    for (int i = 0; i < 2; ++i) {
        const int flat = i * 256 + threadIdx.x;  // 0..511
        const int d    = flat >> 2;              // 0..127
        const int q    = flat & 3;               // f32x4 index within 16-n chunk
        const int nn   = q << 2;
        f32x4 v;
        v.x = lds[(nn + 0) * (S4 * 4) + d];
        v.y = lds[(nn + 1) * (S4 * 4) + d];
        v.z = lds[(nn + 2) * (S4 * 4) + d];
        v.w = lds[(nn + 3) * (S4 * 4) + d];
        __builtin_nontemporal_store(
            v, reinterpret_cast<f32x4*>(outb + (size_t)d * SEQ_N) + q);
    }
}

extern "C" void kernel_launch(void* const* d_in, const int* in_sizes, int n_in,
                              void* d_out, int out_size, void* d_ws, size_t ws_size,
                              hipStream_t stream) {
    const int*   seq = (const int*)d_in[0];
    const float* emb = (const float*)d_in[1];
    float*       out = (float*)d_out;

    const int grid = BATCH * (SEQ_N / NTILE) * (EMBED_DIM / DHALF);  // 2048
    embed_gather_transpose<<<grid, 256, 0, stream>>>(seq, emb, out);
}